// Round 13
// baseline (196.633 us; speedup 1.0000x reference)
//
#include <hip/hip_runtime.h>
#include <cmath>

#define BB   2
#define LL   2048
#define DIMD 1024
#define NS   16
#define KC   4
#define ML   (BB*LL)        // 4096 rows (B*L)
#define XZ_N (2*DIMD)       // 2048
#define XD_N (2*NS + DIMD)  // 1056
#define LC   16             // scan chunk length
#define NC   (LL/LC)        // 128 chunks per sequence

typedef __attribute__((ext_vector_type(8))) short bf16x8;   // 8 bf16 (4 VGPRs)
typedef __attribute__((ext_vector_type(4))) float f32x4;    // MFMA acc

__device__ __forceinline__ unsigned short f2bf(float f) {
    union { float f; unsigned u; } v; v.f = f;
    unsigned r = v.u + 0x7FFF + ((v.u >> 16) & 1);   // round-to-nearest-even
    return (unsigned short)(r >> 16);
}
__device__ __forceinline__ float bf2f(unsigned short u) {
    union { unsigned u; float f; } v; v.u = (unsigned)u << 16;
    return v.f;
}
__device__ __forceinline__ float silu_f(float a) {
    return a / (1.f + __expf(-a));
}
__device__ __forceinline__ void dt_decay(float raw, float& dt, float& e) {
    const float t = __expf(fminf(raw, 80.f));
    e  = 1.f / (1.f + t);
    dt = (raw > 15.f) ? raw : -__logf(e);
}

// ---------------------------------------------------------------------------
// Fused f32 -> bf16 conversion for x + the 3 weight matrices (one launch).
// ---------------------------------------------------------------------------
__global__ __launch_bounds__(256) void cvt_all(
    const float* __restrict__ s0, unsigned short* __restrict__ d0, int n0,
    const float* __restrict__ s1, unsigned short* __restrict__ d1, int n1,
    const float* __restrict__ s2, unsigned short* __restrict__ d2, int n2,
    const float* __restrict__ s3, unsigned short* __restrict__ d3, int n3)
{
    int i = blockIdx.x * blockDim.x + threadIdx.x;
    const float* src; unsigned short* dst;
    if (i < n0)                { src = s0; dst = d0; }
    else if ((i -= n0) < n1)   { src = s1; dst = d1; }
    else if ((i -= n1) < n2)   { src = s2; dst = d2; }
    else if ((i -= n2) < n3)   { src = s3; dst = d3; }
    else return;
    float4 f = ((const float4*)src)[i];
    ushort4 o;
    o.x = f2bf(f.x); o.y = f2bf(f.y); o.z = f2bf(f.z); o.w = f2bf(f.w);
    ((ushort4*)dst)[i] = o;
}

// ---------------------------------------------------------------------------
// bf16 MFMA GEMM, C = A[M,K] @ W[N,K]^T. 128x128 tile (halves A-panel
// staging re-reads vs 128x64 — R10 FETCH counter: 3x over-fetch, all pipes
// <=22% -> L2/L3-staging-BW bound), BK=64, 4 waves in 2x2, acc[4][4] of
// mfma_f32_16x16x32_bf16, XOR-8 LDS swizzle, global_load_lds w=16,
// double-buffered + counted vmcnt against iteration-old loads (R6/R8).
//
// CONV=true (GEMM1): depthwise conv(K=4)+SiLU fused in epilogue. A-tile is
// 144 rows (bm-16..bm+127), SHIFTED for ALL blocks of this instantiation —
// so the extra 16-row load MUST be unconditional (R12 bug: gating it on
// doConv left rows 128..143 garbage in z-half blocks -> NaN). vmcnt is
// uniform 9 (CONV) / 8 (else). Boundary conv rows via 2 accx fragments/wave
// (doConv blocks only). Epilogue: acc -> LDS f32 stride 132 (2-way banks),
// rolling-window conv, write xc f32 + xcb bf16. Conv inputs are the same
// MFMA accumulation -> bit-identical outputs.
// ---------------------------------------------------------------------------
template<bool CONV>
__global__ __launch_bounds__(256) void gemm_mfma_bt(
    const unsigned short* __restrict__ A,
    const unsigned short* __restrict__ Bw,
    float* __restrict__ C,
    unsigned short* __restrict__ zb,
    const float* __restrict__ cw,
    const float* __restrict__ cb,
    float* __restrict__ xcf,
    unsigned short* __restrict__ xcbo,
    int M, int N, int K, int nsplit)
{
    constexpr int AROWS = CONV ? 144 : 128;
    constexpr int XPAD  = 132;   // f32 row stride for conv scratch
    // CONV: conv scratch 144*132*4 = 76032 B dominates staging 69632 B.
    constexpr int SMEM_SHORTS = CONV ? 38016 : (2 * 128 * 64 + 2 * 128 * 64);
    __shared__ short smem[SMEM_SHORTS];

    // XCD-aware bijective swizzle (grids 512 / 288 / 256, all %8==0)
    const int nwg  = gridDim.x * gridDim.y;
    int wgid = blockIdx.y * gridDim.x + blockIdx.x;
    const int cpx = nwg >> 3;
    wgid = (wgid & 7) * cpx + (wgid >> 3);
    const int bx = wgid % gridDim.x;
    const int by = wgid / gridDim.x;

    const int tid  = threadIdx.x;
    const int lane = tid & 63;
    const int wave = tid >> 6;
    const int bm = by * 128;
    const int bn = bx * 128;
    const int wm = (wave >> 1) * 64;   // 2x2 wave grid
    const int wn = (wave & 1) * 64;
    const int l15  = lane & 15;
    const int quad = lane >> 4;

    const bool doConv = CONV && (bn < nsplit);

    f32x4 acc[4][4];
    #pragma unroll
    for (int i = 0; i < 4; ++i)
        #pragma unroll
        for (int j = 0; j < 4; ++j)
            acc[i][j] = (f32x4){0.f, 0.f, 0.f, 0.f};
    f32x4 accx[2];
    accx[0] = (f32x4){0.f, 0.f, 0.f, 0.f};
    accx[1] = (f32x4){0.f, 0.f, 0.f, 0.f};

    const int NK = K >> 6;   // 16 at all call sites

    // stage one 64-deep K-tile: 4 A + (CONV: 1 extra A, UNCONDITIONAL) + 4 B
    auto stage = [&](int s, int k0) {
        short* Abase = smem + (size_t)s * (AROWS * 64);
        short* Bbase = smem + 2 * (AROWS * 64) + (size_t)s * (128 * 64);
        #pragma unroll
        for (int q = 0; q < 4; ++q) {
            const int ci = q * 256 + tid;
            const int srow = ci >> 3;
            const int cc = (ci & 7) ^ (srow & 7);
            short* ldsA = Abase + (size_t)(q * 256 + (tid & ~63)) * 8;
            int ra = CONV ? (bm - 16 + srow) : (bm + srow);
            if (CONV && ra < 0) ra = 0;     // bm=0 pad rows (masked in conv)
            const unsigned short* ga = A + (size_t)ra * K + k0 + cc * 8;
            __builtin_amdgcn_global_load_lds(
                (const __attribute__((address_space(1))) void*)ga,
                (__attribute__((address_space(3))) void*)ldsA, 16, 0, 0);
        }
        if constexpr (CONV) {
            // srows 128..143 (global bm+112..bm+127) — read by EVERY block's
            // main fragments (tile is shifted +16), so never gate on doConv.
            if (lane < 32) {
                const int ci5 = 1024 + wave * 32 + lane;
                const int srow = ci5 >> 3;
                const int cc = (ci5 & 7) ^ (srow & 7);
                short* ldsA = Abase + (size_t)(1024 + wave * 32) * 8;
                const unsigned short* ga =
                    A + (size_t)(bm - 16 + srow) * K + k0 + cc * 8;
                __builtin_amdgcn_global_load_lds(
                    (const __attribute__((address_space(1))) void*)ga,
                    (__attribute__((address_space(3))) void*)ldsA, 16, 0, 0);
            }
        }
        #pragma unroll
        for (int q = 0; q < 4; ++q) {
            const int ci = q * 256 + tid;
            const int r  = ci >> 3;
            const int cc = (ci & 7) ^ (r & 7);
            short* ldsB = Bbase + (size_t)(q * 256 + (tid & ~63)) * 8;
            int rb = bn + r; if (rb > N - 1) rb = N - 1;
            const unsigned short* gb = Bw + (size_t)rb * K + k0 + cc * 8;
            __builtin_amdgcn_global_load_lds(
                (const __attribute__((address_space(1))) void*)gb,
                (__attribute__((address_space(3))) void*)ldsB, 16, 0, 0);
        }
    };

    stage(0, 0);   // prologue: tile 0 in flight

    int cur = 0;
    for (int t = 0; t < NK; ++t) {
        if (t + 1 < NK) {
            stage(cur ^ 1, (t + 1) * 64);
            if constexpr (CONV)
                asm volatile("s_waitcnt vmcnt(9)" ::: "memory");
            else
                asm volatile("s_waitcnt vmcnt(8)" ::: "memory");
        } else {
            asm volatile("s_waitcnt vmcnt(0)" ::: "memory");
        }
        __builtin_amdgcn_s_barrier();

        const short* Ab = smem + (size_t)cur * (AROWS * 64);
        const short* Bb = smem + 2 * (AROWS * 64) + (size_t)cur * (128 * 64);
        #pragma unroll
        for (int kh = 0; kh < 2; ++kh) {
            bf16x8 af[4], bfr[4];
            #pragma unroll
            for (int i = 0; i < 4; ++i) {
                const int srow = (CONV ? 16 : 0) + wm + i * 16 + l15;
                const int pc  = (kh * 4 + quad) ^ (srow & 7);
                af[i] = *(const bf16x8*)(Ab + srow * 64 + pc * 8);
            }
            #pragma unroll
            for (int j = 0; j < 4; ++j) {
                const int row = wn + j * 16 + l15;
                const int pc  = (kh * 4 + quad) ^ (row & 7);
                bfr[j] = *(const bf16x8*)(Bb + row * 64 + pc * 8);
            }
            #pragma unroll
            for (int i = 0; i < 4; ++i)
                #pragma unroll
                for (int j = 0; j < 4; ++j)
                    acc[i][j] = __builtin_amdgcn_mfma_f32_16x16x32_bf16(
                        af[i], bfr[j], acc[i][j], 0, 0, 0);
            if (doConv) {
                // boundary rows bm-16..bm-1 (storage 0..15) x cols
                // wave*32..wave*32+31 (2 fragments; static indices)
                const int pcA = (kh * 4 + quad) ^ (l15 & 7);
                bf16x8 afx = *(const bf16x8*)(Ab + l15 * 64 + pcA * 8);
                {
                    const int rowB = wave * 32 + l15;
                    const int pcB = (kh * 4 + quad) ^ (rowB & 7);
                    bf16x8 bfx = *(const bf16x8*)(Bb + rowB * 64 + pcB * 8);
                    accx[0] = __builtin_amdgcn_mfma_f32_16x16x32_bf16(
                        afx, bfx, accx[0], 0, 0, 0);
                }
                {
                    const int rowB = wave * 32 + 16 + l15;
                    const int pcB = (kh * 4 + quad) ^ (rowB & 7);
                    bf16x8 bfx = *(const bf16x8*)(Bb + rowB * 64 + pcB * 8);
                    accx[1] = __builtin_amdgcn_mfma_f32_16x16x32_bf16(
                        afx, bfx, accx[1], 0, 0, 0);
                }
            }
        }

        if (t + 1 < NK) __builtin_amdgcn_s_barrier();
        cur ^= 1;
    }

    if (doConv) {
        // ---- fused conv epilogue ----
        __syncthreads();                       // all LDS reads retired
        float* xcs = (float*)smem;             // 144*132*4 = 76032 B (fits)
        #pragma unroll
        for (int i = 0; i < 4; ++i)
            #pragma unroll
            for (int j = 0; j < 4; ++j)
                #pragma unroll
                for (int r = 0; r < 4; ++r)
                    xcs[(16 + wm + i * 16 + quad * 4 + r) * XPAD
                        + wn + j * 16 + l15] = acc[i][j][r];
        #pragma unroll
        for (int jx = 0; jx < 2; ++jx)
            #pragma unroll
            for (int r = 0; r < 4; ++r)
                xcs[(quad * 4 + r) * XPAD + wave * 32 + jx * 16 + l15]
                    = accx[jx][r];
        __syncthreads();

        // rolling window: thread owns col tid&127, rows (tid>>7)*64 .. +63
        const int col = tid & 127;
        const int gc  = bn + col;
        const float4 wv  = ((const float4*)cw)[gc];
        const float  bvv = cb[gc];
        const int r0 = (tid >> 7) * 64;
        float xm3 = xcs[(r0 + 13) * XPAD + col];
        float xm2 = xcs[(r0 + 14) * XPAD + col];
        float xm1 = xcs[(r0 + 15) * XPAD + col];
        #pragma unroll
        for (int k = 0; k < 64; ++k) {
            const int r  = r0 + k;
            const int gr = bm + r;
            const int l  = gr & (LL - 1);
            const float xm0 = xcs[(r + 16) * XPAD + col];
            const float a = bvv + wv.x * ((l >= 3) ? xm3 : 0.f)
                                + wv.y * ((l >= 2) ? xm2 : 0.f)
                                + wv.z * ((l >= 1) ? xm1 : 0.f)
                                + wv.w * xm0;
            const float v = silu_f(a);
            xcf[(size_t)gr * DIMD + gc]  = v;
            xcbo[(size_t)gr * DIMD + gc] = f2bf(v);
            xm3 = xm2; xm2 = xm1; xm1 = xm0;
        }
    } else {
        #pragma unroll
        for (int i = 0; i < 4; ++i) {
            const int rbase = bm + wm + i * 16 + quad * 4;
            #pragma unroll
            for (int j = 0; j < 4; ++j) {
                const int colc = bn + wn + j * 16 + l15;
                if (colc < nsplit) {
                    #pragma unroll
                    for (int r = 0; r < 4; ++r)
                        C[(size_t)(rbase + r) * nsplit + colc] = acc[i][j][r];
                } else if (colc < N) {
                    const int zc = colc - nsplit;
                    #pragma unroll
                    for (int r = 0; r < 4; ++r)
                        zb[(size_t)(rbase + r) * DIMD + zc]
                            = f2bf(silu_f(acc[i][j][r]));
                }
            }
        }
    }
}

// ---------------------------------------------------------------------------
// Scan pass 1 (LC=16): local scan from h=0; emit h[16] + S=sum(dt).
// ---------------------------------------------------------------------------
__global__ __launch_bounds__(256) void scan_part1(const float* __restrict__ xdbl,
                                                  const float* __restrict__ xc,
                                                  float* __restrict__ hfin,
                                                  float* __restrict__ Ssum)
{
    __shared__ float Bsh[LC][NS];   // 1 KB

    const int tid = threadIdx.x;
    const int idx = blockIdx.x * 256 + tid;   // (b, c, d)
    const int d   = idx & (DIMD - 1);
    const int bc  = idx >> 10;
    const int c   = bc & (NC - 1);
    const int b   = bc >> 7;
    const int l0  = c * LC;

    const float* xdbl_p = xdbl + ((size_t)b * LL + l0) * XD_N;
    const float* xc_p   = xc   + ((size_t)b * LL + l0) * DIMD + d;

    if (tid < LC * NS / 4) {               // 64 threads stage 16x16 B block
        const int l = tid >> 2, q = tid & 3;
        ((float4*)&Bsh[l][0])[q] = ((const float4*)(xdbl_p + (size_t)l * XD_N))[q];
    }
    __syncthreads();

    float raw[LC], xcv[LC];
    #pragma unroll
    for (int i = 0; i < LC; ++i) raw[i] = xdbl_p[(size_t)i * XD_N + 2 * NS + d];
    #pragma unroll
    for (int i = 0; i < LC; ++i) xcv[i] = xc_p[(size_t)i * DIMD];

    float e[LC], dx[LC];
    float S = 0.f;
    #pragma unroll
    for (int i = 0; i < LC; ++i) {
        float dt, ev;
        dt_decay(raw[i], dt, ev);
        S += dt;
        e[i]  = ev;
        dx[i] = dt * xcv[i];
    }

    float h[NS];
    #pragma unroll
    for (int n = 0; n < NS; ++n) h[n] = 0.f;

    #pragma unroll
    for (int i = 0; i < LC; ++i) {
        const float4* BC = (const float4*)&Bsh[i][0];
        const float4 B0 = BC[0], B1 = BC[1], B2 = BC[2], B3 = BC[3];
        const float ev = e[i], dxv = dx[i];
        const float e2 = ev * ev, e4 = e2 * e2;
        float p0 = ev, p1 = e2, p2 = e2 * ev, p3 = e4;
        h[0]  = fmaf(h[0],  p0, dxv * B0.x);
        h[1]  = fmaf(h[1],  p1, dxv * B0.y);
        h[2]  = fmaf(h[2],  p2, dxv * B0.z);
        h[3]  = fmaf(h[3],  p3, dxv * B0.w);
        p0 *= e4; p1 *= e4; p2 *= e4; p3 *= e4;
        h[4]  = fmaf(h[4],  p0, dxv * B1.x);
        h[5]  = fmaf(h[5],  p1, dxv * B1.y);
        h[6]  = fmaf(h[6],  p2, dxv * B1.z);
        h[7]  = fmaf(h[7],  p3, dxv * B1.w);
        p0 *= e4; p1 *= e4; p2 *= e4; p3 *= e4;
        h[8]  = fmaf(h[8],  p0, dxv * B2.x);
        h[9]  = fmaf(h[9],  p1, dxv * B2.y);
        h[10] = fmaf(h[10], p2, dxv * B2.z);
        h[11] = fmaf(h[11], p3, dxv * B2.w);
        p0 *= e4; p1 *= e4; p2 *= e4; p3 *= e4;
        h[12] = fmaf(h[12], p0, dxv * B3.x);
        h[13] = fmaf(h[13], p1, dxv * B3.y);
        h[14] = fmaf(h[14], p2, dxv * B3.z);
        h[15] = fmaf(h[15], p3, dxv * B3.w);
    }

    float4* hf = (float4*)(hfin + (size_t)idx * NS);
    #pragma unroll
    for (int n = 0; n < 4; ++n) hf[n] = ((float4*)h)[n];
    Ssum[idx] = S;
}

// ---------------------------------------------------------------------------
// Scan pass 2 (cross-chunk combine), PARALLEL-COMPOSITE (R8, proven +2.7us).
// ---------------------------------------------------------------------------
#define NGRP 8
#define CPG  (NC / NGRP)   // 16 chunks per group
__global__ __launch_bounds__(256) void scan_combine(float* __restrict__ hfin,
                                                    const float* __restrict__ Ssum)
{
    __shared__ float Ash[2][NGRP][NS];
    __shared__ float Bsh2[2][NGRP][NS];

    const int tid = threadIdx.x;
    const int n   = tid & (NS - 1);
    const int g   = (tid >> 4) & (NGRP - 1);
    const int d2  = tid >> 7;                    // 0..1
    const int bd  = blockIdx.x * 2 + d2;         // flat b*DIMD+d
    const int d   = bd & (DIMD - 1);
    const int b   = bd >> 10;
    const float np1 = (float)(n + 1);
    const int c0 = g * CPG;

    float e[CPG], hb[CPG];
    #pragma unroll
    for (int j = 0; j < CPG; ++j) {
        const size_t base = ((size_t)(b * NC + c0 + j) * DIMD + d);
        const float S = Ssum[base];
        hb[j] = hfin[base * NS + n];
        e[j]  = __expf(-S * np1);
    }

    float A = 1.f, Bv = 0.f;
    #pragma unroll
    for (int j = 0; j < CPG; ++j) { Bv = fmaf(Bv, e[j], hb[j]); A *= e[j]; }

    Ash[d2][g][n] = A;  Bsh2[d2][g][n] = Bv;
    __syncthreads();

    float hc = 0.f;                       // exclusive scan over groups < g
    for (int j = 0; j < g; ++j) hc = fmaf(hc, Ash[d2][j][n], Bsh2[d2][j][n]);

    #pragma unroll
    for (int j = 0; j < CPG; ++j) {
        const size_t o = ((size_t)(b * NC + c0 + j) * DIMD + d) * NS + n;
        hfin[o] = hc;
        hc = fmaf(hc, e[j], hb[j]);
    }
}

// ---------------------------------------------------------------------------
// Scan pass 3 (LC=16): seeded re-scan + y + D*xc + z-gate + bf16 store.
// ---------------------------------------------------------------------------
__global__ __launch_bounds__(256) void scan_part2(const float* __restrict__ xdbl,
                                                  const float* __restrict__ xc,
                                                  const unsigned short* __restrict__ zb,
                                                  const float* __restrict__ hfin,
                                                  const float* __restrict__ Dp,
                                                  unsigned short* __restrict__ yout)
{
    __shared__ float BCs[LC][2 * NS];   // 2 KB

    const int tid = threadIdx.x;
    const int idx = blockIdx.x * 256 + tid;
    const int d   = idx & (DIMD - 1);
    const int bc  = idx >> 10;
    const int c   = bc & (NC - 1);
    const int b   = bc >> 7;
    const int l0  = c * LC;

    const float* xdbl_p = xdbl + ((size_t)b * LL + l0) * XD_N;
    const float* xc_p   = xc   + ((size_t)b * LL + l0) * DIMD + d;
    const unsigned short* zb_p = zb + ((size_t)b * LL + l0) * DIMD + d;
    unsigned short* y_p = yout + ((size_t)b * LL + l0) * DIMD + d;

    if (tid < LC * 2 * NS / 4) {           // 128 threads stage 16x32 B|C block
        const int l = tid >> 3, q = tid & 7;
        ((float4*)&BCs[l][0])[q] = ((const float4*)(xdbl_p + (size_t)l * XD_N))[q];
    }
    __syncthreads();

    float raw[LC], xcv[LC], zg[LC];
    #pragma unroll
    for (int i = 0; i < LC; ++i) raw[i] = xdbl_p[(size_t)i * XD_N + 2 * NS + d];
    #pragma unroll
    for (int i = 0; i < LC; ++i) xcv[i] = xc_p[(size_t)i * DIMD];
    #pragma unroll
    for (int i = 0; i < LC; ++i) zg[i] = bf2f(zb_p[(size_t)i * DIMD]);

    float e[LC], dx[LC];
    #pragma unroll
    for (int i = 0; i < LC; ++i) {
        float dt, ev;
        dt_decay(raw[i], dt, ev);
        e[i]  = ev;
        dx[i] = dt * xcv[i];
    }

    const float Dv = Dp[d];
    float h[NS];
    {
        const float4* hf = (const float4*)(hfin + (size_t)idx * NS);
        #pragma unroll
        for (int n = 0; n < 4; ++n) ((float4*)h)[n] = hf[n];
    }

    #pragma unroll
    for (int i = 0; i < LC; ++i) {
        const float4* BC = (const float4*)&BCs[i][0];
        const float4 B0 = BC[0], B1 = BC[1], B2 = BC[2], B3 = BC[3];
        const float4 C0 = BC[4], C1 = BC[5], C2 = BC[6], C3 = BC[7];
        const float ev = e[i], dxv = dx[i];
        const float e2 = ev * ev, e4 = e2 * e2;
        float p0 = ev, p1 = e2, p2 = e2 * ev, p3 = e4;
        float y0, y1, y2, y3;
        h[0]  = fmaf(h[0],  p0, dxv * B0.x); y0 = h[0]  * C0.x;
        h[1]  = fmaf(h[1],  p1, dxv * B0.y); y1 = h[1]  * C0.y;
        h[2]  = fmaf(h[2],  p2, dxv * B0.z); y2 = h[2]  * C0.z;
        h[3]  = fmaf(h[3],  p3, dxv * B0.w); y3 = h[3]  * C0.w;
        p0 *= e4; p1 *= e4; p2 *= e4; p3 *= e4;
        h[4]  = fmaf(h[4],  p0, dxv * B1.x); y0 = fmaf(h[4],  C1.x, y0);
        h[5]  = fmaf(h[5],  p1, dxv * B1.y); y1 = fmaf(h[5],  C1.y, y1);
        h[6]  = fmaf(h[6],  p2, dxv * B1.z); y2 = fmaf(h[6],  C1.z, y2);
        h[7]  = fmaf(h[7],  p3, dxv * B1.w); y3 = fmaf(h[7],  C1.w, y3);
        p0 *= e4; p1 *= e4; p2 *= e4; p3 *= e4;
        h[8]  = fmaf(h[8],  p0, dxv * B2.x); y0 = fmaf(h[8],  C2.x, y0);
        h[9]  = fmaf(h[9],  p1, dxv * B2.y); y1 = fmaf(h[9],  C2.y, y1);
        h[10] = fmaf(h[10], p2, dxv * B2.z); y2 = fmaf(h[10], C2.z, y2);
        h[11] = fmaf(h[11], p3, dxv * B2.w); y3 = fmaf(h[11], C2.w, y3);
        p0 *= e4; p1 *= e4; p2 *= e4; p3 *= e4;
        h[12] = fmaf(h[12], p0, dxv * B3.x); y0 = fmaf(h[12], C3.x, y0);
        h[13] = fmaf(h[13], p1, dxv * B3.y); y1 = fmaf(h[13], C3.y, y1);
        h[14] = fmaf(h[14], p2, dxv * B3.z); y2 = fmaf(h[14], C3.z, y2);
        h[15] = fmaf(h[15], p3, dxv * B3.w); y3 = fmaf(h[15], C3.w, y3);

        const float y  = (y0 + y1) + (y2 + y3);
        const float yv = fmaf(Dv, xcv[i], y);
        y_p[(size_t)i * DIMD] = f2bf(yv * zg[i]);
    }
}

extern "C" void kernel_launch(void* const* d_in, const int* in_sizes, int n_in,
                              void* d_out, int out_size, void* d_ws, size_t ws_size,
                              hipStream_t stream)
{
    const float* x          = (const float*)d_in[0];
    const float* in_proj_w  = (const float*)d_in[1];
    const float* conv_w     = (const float*)d_in[2];
    const float* conv_b     = (const float*)d_in[3];
    const float* x_proj_w   = (const float*)d_in[4];
    const float* D_param    = (const float*)d_in[5];
    const float* out_proj_w = (const float*)d_in[6];
    float* out = (float*)d_out;

    // workspace layout (xcraw slot retired — conv fused into GEMM1)
    float* xcraw = (float*)d_ws;                              // (unused)
    float* xc    = xcraw + (size_t)ML * DIMD;                 // ML*DIMD f32
    float* xdbl  = xc    + (size_t)ML * DIMD;                 // ML*XD_N f32
    unsigned short* zb  = (unsigned short*)(xdbl + (size_t)ML * XD_N); // ML*DIMD bf16
    unsigned short* xb  = zb  + (size_t)ML * DIMD;            // ML*DIMD bf16
    unsigned short* xcb = xb  + (size_t)ML * DIMD;            // ML*DIMD bf16
    unsigned short* wb1 = xcb + (size_t)ML * DIMD;            // XZ_N*DIMD bf16
    unsigned short* wb2 = wb1 + (size_t)XZ_N * DIMD;          // XD_N*DIMD bf16
    unsigned short* wb3 = wb2 + (size_t)XD_N * DIMD;          // DIMD*DIMD bf16
    float* hfin = (float*)(wb3 + (size_t)DIMD * DIMD);        // B*NC*DIMD*NS f32
    float* Ssum = hfin + (size_t)BB * NC * DIMD * NS;         // B*NC*DIMD f32
    unsigned short* yb  = xb;    // xb dead after GEMM1; reuse for scan output

    const int n0 = ML * DIMD / 4, n1 = XZ_N * DIMD / 4,
              n2 = XD_N * DIMD / 4, n3 = DIMD * DIMD / 4;
    const int ncvt = n0 + n1 + n2 + n3;

    // 0) all f32->bf16 conversions in one launch
    cvt_all<<<(ncvt + 255) / 256, 256, 0, stream>>>(
        x, xb, n0, in_proj_w, wb1, n1, x_proj_w, wb2, n2, out_proj_w, wb3, n3);

    // 1) xz = x @ in_proj_w.T, FUSED with depthwise conv+SiLU:
    //    x_c half -> conv -> xc (f32) + xcb (bf16); z half -> silu bf16 zb
    //    grid 16x32 = 512 blocks
    gemm_mfma_bt<true><<<dim3(XZ_N / 128, ML / 128), 256, 0, stream>>>(
        xb, wb1, nullptr, zb, conv_w, conv_b, xc, xcb, ML, XZ_N, DIMD, DIMD);

    // 2) x_dbl = xc @ x_proj_w.T     (4096 x 1056 x 1024); grid 9x32 = 288
    gemm_mfma_bt<false><<<dim3((XD_N + 127) / 128, ML / 128), 256, 0, stream>>>(
        xcb, wb2, xdbl, nullptr, nullptr, nullptr, nullptr, nullptr,
        ML, XD_N, DIMD, XD_N);

    // 3) chunked selective scan (LC=16). Do NOT grid.sync-fuse (prior session:
    //    grid sync forces per-XCD L2 writeback -> 577 MB HBM, 465 us).
    scan_part1<<<(BB * NC * DIMD) / 256, 256, 0, stream>>>(xdbl, xc, hfin, Ssum);
    scan_combine<<<(BB * DIMD) / 2, 256, 0, stream>>>(hfin, Ssum);
    scan_part2<<<(BB * NC * DIMD) / 256, 256, 0, stream>>>(xdbl, xc, zb, hfin,
                                                           D_param, yb);

    // 4) out = y @ out_proj_w.T      (4096 x 1024 x 1024); grid 8x32 = 256
    gemm_mfma_bt<false><<<dim3(DIMD / 128, ML / 128), 256, 0, stream>>>(
        yb, wb3, out, nullptr, nullptr, nullptr, nullptr, nullptr,
        ML, DIMD, DIMD, DIMD);
}

// Round 14
// 188.833 us; speedup vs baseline: 1.0413x; 1.0413x over previous
//
#include <hip/hip_runtime.h>
#include <cmath>

#define BB   2
#define LL   2048
#define DIMD 1024
#define NS   16
#define KC   4
#define ML   (BB*LL)        // 4096 rows (B*L)
#define XZ_N (2*DIMD)       // 2048
#define XD_N (2*NS + DIMD)  // 1056
#define LC   16             // scan chunk length
#define NC   (LL/LC)        // 128 chunks per sequence

typedef __attribute__((ext_vector_type(8))) short bf16x8;   // 8 bf16 (4 VGPRs)
typedef __attribute__((ext_vector_type(4))) float f32x4;    // MFMA acc

__device__ __forceinline__ unsigned short f2bf(float f) {
    union { float f; unsigned u; } v; v.f = f;
    unsigned r = v.u + 0x7FFF + ((v.u >> 16) & 1);   // round-to-nearest-even
    return (unsigned short)(r >> 16);
}
__device__ __forceinline__ float bf2f(unsigned short u) {
    union { unsigned u; float f; } v; v.u = (unsigned)u << 16;
    return v.f;
}
__device__ __forceinline__ float silu_f(float a) {
    return a / (1.f + __expf(-a));
}
__device__ __forceinline__ void dt_decay(float raw, float& dt, float& e) {
    const float t = __expf(fminf(raw, 80.f));
    e  = 1.f / (1.f + t);
    dt = (raw > 15.f) ? raw : -__logf(e);
}

// ---------------------------------------------------------------------------
// Fused f32 -> bf16 conversion for x + the 3 weight matrices (one launch).
// ---------------------------------------------------------------------------
__global__ __launch_bounds__(256) void cvt_all(
    const float* __restrict__ s0, unsigned short* __restrict__ d0, int n0,
    const float* __restrict__ s1, unsigned short* __restrict__ d1, int n1,
    const float* __restrict__ s2, unsigned short* __restrict__ d2, int n2,
    const float* __restrict__ s3, unsigned short* __restrict__ d3, int n3)
{
    int i = blockIdx.x * blockDim.x + threadIdx.x;
    const float* src; unsigned short* dst;
    if (i < n0)                { src = s0; dst = d0; }
    else if ((i -= n0) < n1)   { src = s1; dst = d1; }
    else if ((i -= n1) < n2)   { src = s2; dst = d2; }
    else if ((i -= n2) < n3)   { src = s3; dst = d3; }
    else return;
    float4 f = ((const float4*)src)[i];
    ushort4 o;
    o.x = f2bf(f.x); o.y = f2bf(f.y); o.z = f2bf(f.z); o.w = f2bf(f.w);
    ((ushort4*)dst)[i] = o;
}

// ---------------------------------------------------------------------------
// bf16 MFMA GEMM, C = A[M,K] @ W[N,K]^T. 128x64 tile, BK=64, 4 waves,
// acc[2][4] of mfma_f32_16x16x32_bf16, XOR-8 LDS swizzle, global_load_lds
// w=16, double-buffered + counted vmcnt against iteration-old loads.
// SESSION-FINAL geometry: 7 structural variants tested (R1-R13: 128^2 both
// sync styles, 1-wave 64^2, 2-phase drain0, depth-2 ring, BK=32 hi-occ,
// 128^2 counted) — ALL lost to this config. GEMM structure closed.
//
// CONV=true (GEMM1): depthwise conv (K=4)+SiLU fused into the epilogue
// (R10: -15us). A-tile extended to 144 rows (bm-16..bm+127) via one extra
// lane-masked load + one extra MFMA fragment per kh. Extra load is
// UNCONDITIONAL in the CONV instantiation (R12 NaN lesson: every block's
// main fragments read the shifted rows). Epilogue (R11: -8us): acc -> LDS
// f32 ROW STRIDE 68 (4*68 = 16 mod 32 banks -> quad writes 2-way), then
// ROLLING-WINDOW conv: thread owns one col x 32 contiguous rows, 1 LDS
// read/row. xcs = 144*68*4 = 39168 B aliases carved smem (53248 B).
// Conv expression unchanged -> bit-identical. CONV=false: R8-proven path.
// ---------------------------------------------------------------------------
template<bool CONV>
__global__ __launch_bounds__(256) void gemm_mfma_bt(
    const unsigned short* __restrict__ A,
    const unsigned short* __restrict__ Bw,
    float* __restrict__ C,
    unsigned short* __restrict__ zb,
    const float* __restrict__ cw,
    const float* __restrict__ cb,
    float* __restrict__ xcf,
    unsigned short* __restrict__ xcbo,
    int M, int N, int K, int nsplit)
{
    constexpr int AROWS = CONV ? 144 : 128;
    constexpr int XPAD  = 68;   // f32 row stride for conv scratch (bank fix)
    // carved layout: As[0], As[1], Bs[0], Bs[1] contiguous
    __shared__ short smem[2 * AROWS * 64 + 2 * 64 * 64];

    // XCD-aware bijective swizzle (grids 1024 / 544 / 512, all %8==0)
    const int nwg  = gridDim.x * gridDim.y;
    int wgid = blockIdx.y * gridDim.x + blockIdx.x;
    const int cpx = nwg >> 3;
    wgid = (wgid & 7) * cpx + (wgid >> 3);
    const int bx = wgid % gridDim.x;
    const int by = wgid / gridDim.x;

    const int tid  = threadIdx.x;
    const int lane = tid & 63;
    const int wave = tid >> 6;
    const int bm = by * 128;
    const int bn = bx * 64;
    const int wm = wave * 32;
    const int l15  = lane & 15;
    const int quad = lane >> 4;

    const bool doConv = CONV && (bn < nsplit);

    f32x4 acc[2][4];
    #pragma unroll
    for (int i = 0; i < 2; ++i)
        #pragma unroll
        for (int j = 0; j < 4; ++j)
            acc[i][j] = (f32x4){0.f, 0.f, 0.f, 0.f};
    f32x4 accx = (f32x4){0.f, 0.f, 0.f, 0.f};

    const int NK = K >> 6;   // 16 at all call sites

    // stage one 64-deep K-tile: 4 A + (CONV: 1 extra A) + 2 B instrs
    auto stage = [&](int s, int k0) {
        short* Abase = smem + (size_t)s * (AROWS * 64);
        short* Bbase = smem + 2 * (AROWS * 64) + (size_t)s * (64 * 64);
        #pragma unroll
        for (int q = 0; q < 4; ++q) {
            const int ci = q * 256 + tid;
            const int srow = ci >> 3;
            const int cc = (ci & 7) ^ (srow & 7);
            short* ldsA = Abase + (size_t)(q * 256 + (tid & ~63)) * 8;
            int ra = CONV ? (bm - 16 + srow) : (bm + srow);
            if (CONV && ra < 0) ra = 0;     // bm=0 pad rows (masked in conv)
            const unsigned short* ga = A + (size_t)ra * K + k0 + cc * 8;
            __builtin_amdgcn_global_load_lds(
                (const __attribute__((address_space(1))) void*)ga,
                (__attribute__((address_space(3))) void*)ldsA, 16, 0, 0);
        }
        if constexpr (CONV) {
            if (lane < 32) {   // srows 128..143, UNCONDITIONAL (R12 lesson)
                const int ci5 = 1024 + wave * 32 + lane;
                const int srow = ci5 >> 3;
                const int cc = (ci5 & 7) ^ (srow & 7);
                short* ldsA = Abase + (size_t)(1024 + wave * 32) * 8;
                const unsigned short* ga =
                    A + (size_t)(bm - 16 + srow) * K + k0 + cc * 8;
                __builtin_amdgcn_global_load_lds(
                    (const __attribute__((address_space(1))) void*)ga,
                    (__attribute__((address_space(3))) void*)ldsA, 16, 0, 0);
            }
        }
        #pragma unroll
        for (int q = 0; q < 2; ++q) {
            const int ci = q * 256 + tid;
            const int r  = ci >> 3;
            const int cc = (ci & 7) ^ (r & 7);
            short* ldsB = Bbase + (size_t)(q * 256 + (tid & ~63)) * 8;
            int rb = bn + r; if (rb > N - 1) rb = N - 1;
            const unsigned short* gb = Bw + (size_t)rb * K + k0 + cc * 8;
            __builtin_amdgcn_global_load_lds(
                (const __attribute__((address_space(1))) void*)gb,
                (__attribute__((address_space(3))) void*)ldsB, 16, 0, 0);
        }
    };

    stage(0, 0);   // prologue: tile 0 in flight

    int cur = 0;
    for (int t = 0; t < NK; ++t) {
        if (t + 1 < NK) {
            stage(cur ^ 1, (t + 1) * 64);
            if constexpr (CONV)
                asm volatile("s_waitcnt vmcnt(7)" ::: "memory");
            else
                asm volatile("s_waitcnt vmcnt(6)" ::: "memory");
        } else {
            asm volatile("s_waitcnt vmcnt(0)" ::: "memory");
        }
        __builtin_amdgcn_s_barrier();

        const short* Ab = smem + (size_t)cur * (AROWS * 64);
        const short* Bb = smem + 2 * (AROWS * 64) + (size_t)cur * (64 * 64);
        #pragma unroll
        for (int kh = 0; kh < 2; ++kh) {
            bf16x8 af[2], bfr[4];
            #pragma unroll
            for (int i = 0; i < 2; ++i) {
                const int srow = (CONV ? 16 : 0) + wm + i * 16 + l15;
                const int pc  = (kh * 4 + quad) ^ (srow & 7);
                af[i] = *(const bf16x8*)(Ab + srow * 64 + pc * 8);
            }
            #pragma unroll
            for (int j = 0; j < 4; ++j) {
                const int row = j * 16 + l15;
                const int pc  = (kh * 4 + quad) ^ (row & 7);
                bfr[j] = *(const bf16x8*)(Bb + row * 64 + pc * 8);
            }
            #pragma unroll
            for (int i = 0; i < 2; ++i)
                #pragma unroll
                for (int j = 0; j < 4; ++j)
                    acc[i][j] = __builtin_amdgcn_mfma_f32_16x16x32_bf16(
                        af[i], bfr[j], acc[i][j], 0, 0, 0);
            if (doConv) {
                // boundary fragment: A srows 0..15 x B cols wave*16..+15
                const int pcA = (kh * 4 + quad) ^ (l15 & 7);
                bf16x8 afx = *(const bf16x8*)(Ab + l15 * 64 + pcA * 8);
                const int rowB = wave * 16 + l15;
                const int pcB = (kh * 4 + quad) ^ (rowB & 7);
                bf16x8 bfx = *(const bf16x8*)(Bb + rowB * 64 + pcB * 8);
                accx = __builtin_amdgcn_mfma_f32_16x16x32_bf16(
                    afx, bfx, accx, 0, 0, 0);
            }
        }

        if (t + 1 < NK) __builtin_amdgcn_s_barrier();
        cur ^= 1;
    }

    if (doConv) {
        // ---- fused conv epilogue (stride-68 scratch + rolling window) ----
        __syncthreads();                       // all LDS reads retired
        float* xcs = (float*)smem;             // 144*68*4 = 39168 B <= 53248
        #pragma unroll
        for (int i = 0; i < 2; ++i)
            #pragma unroll
            for (int j = 0; j < 4; ++j)
                #pragma unroll
                for (int r = 0; r < 4; ++r)
                    xcs[(16 + wm + i * 16 + quad * 4 + r) * XPAD
                        + j * 16 + l15] = acc[i][j][r];
        #pragma unroll
        for (int r = 0; r < 4; ++r)
            xcs[(quad * 4 + r) * XPAD + wave * 16 + l15] = accx[r];
        __syncthreads();

        // rolling window: thread owns col, rows wave*32..wave*32+31
        const int col = tid & 63;
        const int gc  = bn + col;
        const float4 wv  = ((const float4*)cw)[gc];
        const float  bvv = cb[gc];
        const int r0 = wave * 32;              // local row base
        float xm3 = xcs[(r0 + 13) * XPAD + col];
        float xm2 = xcs[(r0 + 14) * XPAD + col];
        float xm1 = xcs[(r0 + 15) * XPAD + col];
        #pragma unroll
        for (int k = 0; k < 32; ++k) {
            const int r  = r0 + k;
            const int gr = bm + r;
            const int l  = gr & (LL - 1);
            const float xm0 = xcs[(r + 16) * XPAD + col];
            const float a = bvv + wv.x * ((l >= 3) ? xm3 : 0.f)
                                + wv.y * ((l >= 2) ? xm2 : 0.f)
                                + wv.z * ((l >= 1) ? xm1 : 0.f)
                                + wv.w * xm0;
            const float v = silu_f(a);
            xcf[(size_t)gr * DIMD + gc]  = v;
            xcbo[(size_t)gr * DIMD + gc] = f2bf(v);
            xm3 = xm2; xm2 = xm1; xm1 = xm0;
        }
    } else {
        #pragma unroll
        for (int i = 0; i < 2; ++i) {
            const int rbase = bm + wm + i * 16 + quad * 4;
            #pragma unroll
            for (int j = 0; j < 4; ++j) {
                const int colc = bn + j * 16 + l15;
                if (colc < nsplit) {
                    #pragma unroll
                    for (int r = 0; r < 4; ++r)
                        C[(size_t)(rbase + r) * nsplit + colc] = acc[i][j][r];
                } else if (colc < N) {
                    const int zc = colc - nsplit;
                    #pragma unroll
                    for (int r = 0; r < 4; ++r)
                        zb[(size_t)(rbase + r) * DIMD + zc]
                            = f2bf(silu_f(acc[i][j][r]));
                }
            }
        }
    }
}

// ---------------------------------------------------------------------------
// Scan pass 1 (LC=16): local scan from h=0; emit h[16] + S=sum(dt).
// ---------------------------------------------------------------------------
__global__ __launch_bounds__(256) void scan_part1(const float* __restrict__ xdbl,
                                                  const float* __restrict__ xc,
                                                  float* __restrict__ hfin,
                                                  float* __restrict__ Ssum)
{
    __shared__ float Bsh[LC][NS];   // 1 KB

    const int tid = threadIdx.x;
    const int idx = blockIdx.x * 256 + tid;   // (b, c, d)
    const int d   = idx & (DIMD - 1);
    const int bc  = idx >> 10;
    const int c   = bc & (NC - 1);
    const int b   = bc >> 7;
    const int l0  = c * LC;

    const float* xdbl_p = xdbl + ((size_t)b * LL + l0) * XD_N;
    const float* xc_p   = xc   + ((size_t)b * LL + l0) * DIMD + d;

    if (tid < LC * NS / 4) {               // 64 threads stage 16x16 B block
        const int l = tid >> 2, q = tid & 3;
        ((float4*)&Bsh[l][0])[q] = ((const float4*)(xdbl_p + (size_t)l * XD_N))[q];
    }
    __syncthreads();

    float raw[LC], xcv[LC];
    #pragma unroll
    for (int i = 0; i < LC; ++i) raw[i] = xdbl_p[(size_t)i * XD_N + 2 * NS + d];
    #pragma unroll
    for (int i = 0; i < LC; ++i) xcv[i] = xc_p[(size_t)i * DIMD];

    float e[LC], dx[LC];
    float S = 0.f;
    #pragma unroll
    for (int i = 0; i < LC; ++i) {
        float dt, ev;
        dt_decay(raw[i], dt, ev);
        S += dt;
        e[i]  = ev;
        dx[i] = dt * xcv[i];
    }

    float h[NS];
    #pragma unroll
    for (int n = 0; n < NS; ++n) h[n] = 0.f;

    #pragma unroll
    for (int i = 0; i < LC; ++i) {
        const float4* BC = (const float4*)&Bsh[i][0];
        const float4 B0 = BC[0], B1 = BC[1], B2 = BC[2], B3 = BC[3];
        const float ev = e[i], dxv = dx[i];
        const float e2 = ev * ev, e4 = e2 * e2;
        float p0 = ev, p1 = e2, p2 = e2 * ev, p3 = e4;
        h[0]  = fmaf(h[0],  p0, dxv * B0.x);
        h[1]  = fmaf(h[1],  p1, dxv * B0.y);
        h[2]  = fmaf(h[2],  p2, dxv * B0.z);
        h[3]  = fmaf(h[3],  p3, dxv * B0.w);
        p0 *= e4; p1 *= e4; p2 *= e4; p3 *= e4;
        h[4]  = fmaf(h[4],  p0, dxv * B1.x);
        h[5]  = fmaf(h[5],  p1, dxv * B1.y);
        h[6]  = fmaf(h[6],  p2, dxv * B1.z);
        h[7]  = fmaf(h[7],  p3, dxv * B1.w);
        p0 *= e4; p1 *= e4; p2 *= e4; p3 *= e4;
        h[8]  = fmaf(h[8],  p0, dxv * B2.x);
        h[9]  = fmaf(h[9],  p1, dxv * B2.y);
        h[10] = fmaf(h[10], p2, dxv * B2.z);
        h[11] = fmaf(h[11], p3, dxv * B2.w);
        p0 *= e4; p1 *= e4; p2 *= e4; p3 *= e4;
        h[12] = fmaf(h[12], p0, dxv * B3.x);
        h[13] = fmaf(h[13], p1, dxv * B3.y);
        h[14] = fmaf(h[14], p2, dxv * B3.z);
        h[15] = fmaf(h[15], p3, dxv * B3.w);
    }

    float4* hf = (float4*)(hfin + (size_t)idx * NS);
    #pragma unroll
    for (int n = 0; n < 4; ++n) hf[n] = ((float4*)h)[n];
    Ssum[idx] = S;
}

// ---------------------------------------------------------------------------
// Scan pass 2 (cross-chunk combine), PARALLEL-COMPOSITE (R8, proven +2.7us).
// ---------------------------------------------------------------------------
#define NGRP 8
#define CPG  (NC / NGRP)   // 16 chunks per group
__global__ __launch_bounds__(256) void scan_combine(float* __restrict__ hfin,
                                                    const float* __restrict__ Ssum)
{
    __shared__ float Ash[2][NGRP][NS];
    __shared__ float Bsh2[2][NGRP][NS];

    const int tid = threadIdx.x;
    const int n   = tid & (NS - 1);
    const int g   = (tid >> 4) & (NGRP - 1);
    const int d2  = tid >> 7;                    // 0..1
    const int bd  = blockIdx.x * 2 + d2;         // flat b*DIMD+d
    const int d   = bd & (DIMD - 1);
    const int b   = bd >> 10;
    const float np1 = (float)(n + 1);
    const int c0 = g * CPG;

    float e[CPG], hb[CPG];
    #pragma unroll
    for (int j = 0; j < CPG; ++j) {
        const size_t base = ((size_t)(b * NC + c0 + j) * DIMD + d);
        const float S = Ssum[base];
        hb[j] = hfin[base * NS + n];
        e[j]  = __expf(-S * np1);
    }

    float A = 1.f, Bv = 0.f;
    #pragma unroll
    for (int j = 0; j < CPG; ++j) { Bv = fmaf(Bv, e[j], hb[j]); A *= e[j]; }

    Ash[d2][g][n] = A;  Bsh2[d2][g][n] = Bv;
    __syncthreads();

    float hc = 0.f;                       // exclusive scan over groups < g
    for (int j = 0; j < g; ++j) hc = fmaf(hc, Ash[d2][j][n], Bsh2[d2][j][n]);

    #pragma unroll
    for (int j = 0; j < CPG; ++j) {
        const size_t o = ((size_t)(b * NC + c0 + j) * DIMD + d) * NS + n;
        hfin[o] = hc;
        hc = fmaf(hc, e[j], hb[j]);
    }
}

// ---------------------------------------------------------------------------
// Scan pass 3 (LC=16): seeded re-scan + y + D*xc + z-gate + bf16 store.
// ---------------------------------------------------------------------------
__global__ __launch_bounds__(256) void scan_part2(const float* __restrict__ xdbl,
                                                  const float* __restrict__ xc,
                                                  const unsigned short* __restrict__ zb,
                                                  const float* __restrict__ hfin,
                                                  const float* __restrict__ Dp,
                                                  unsigned short* __restrict__ yout)
{
    __shared__ float BCs[LC][2 * NS];   // 2 KB

    const int tid = threadIdx.x;
    const int idx = blockIdx.x * 256 + tid;
    const int d   = idx & (DIMD - 1);
    const int bc  = idx >> 10;
    const int c   = bc & (NC - 1);
    const int b   = bc >> 7;
    const int l0  = c * LC;

    const float* xdbl_p = xdbl + ((size_t)b * LL + l0) * XD_N;
    const float* xc_p   = xc   + ((size_t)b * LL + l0) * DIMD + d;
    const unsigned short* zb_p = zb + ((size_t)b * LL + l0) * DIMD + d;
    unsigned short* y_p = yout + ((size_t)b * LL + l0) * DIMD + d;

    if (tid < LC * 2 * NS / 4) {           // 128 threads stage 16x32 B|C block
        const int l = tid >> 3, q = tid & 7;
        ((float4*)&BCs[l][0])[q] = ((const float4*)(xdbl_p + (size_t)l * XD_N))[q];
    }
    __syncthreads();

    float raw[LC], xcv[LC], zg[LC];
    #pragma unroll
    for (int i = 0; i < LC; ++i) raw[i] = xdbl_p[(size_t)i * XD_N + 2 * NS + d];
    #pragma unroll
    for (int i = 0; i < LC; ++i) xcv[i] = xc_p[(size_t)i * DIMD];
    #pragma unroll
    for (int i = 0; i < LC; ++i) zg[i] = bf2f(zb_p[(size_t)i * DIMD]);

    float e[LC], dx[LC];
    #pragma unroll
    for (int i = 0; i < LC; ++i) {
        float dt, ev;
        dt_decay(raw[i], dt, ev);
        e[i]  = ev;
        dx[i] = dt * xcv[i];
    }

    const float Dv = Dp[d];
    float h[NS];
    {
        const float4* hf = (const float4*)(hfin + (size_t)idx * NS);
        #pragma unroll
        for (int n = 0; n < 4; ++n) ((float4*)h)[n] = hf[n];
    }

    #pragma unroll
    for (int i = 0; i < LC; ++i) {
        const float4* BC = (const float4*)&BCs[i][0];
        const float4 B0 = BC[0], B1 = BC[1], B2 = BC[2], B3 = BC[3];
        const float4 C0 = BC[4], C1 = BC[5], C2 = BC[6], C3 = BC[7];
        const float ev = e[i], dxv = dx[i];
        const float e2 = ev * ev, e4 = e2 * e2;
        float p0 = ev, p1 = e2, p2 = e2 * ev, p3 = e4;
        float y0, y1, y2, y3;
        h[0]  = fmaf(h[0],  p0, dxv * B0.x); y0 = h[0]  * C0.x;
        h[1]  = fmaf(h[1],  p1, dxv * B0.y); y1 = h[1]  * C0.y;
        h[2]  = fmaf(h[2],  p2, dxv * B0.z); y2 = h[2]  * C0.z;
        h[3]  = fmaf(h[3],  p3, dxv * B0.w); y3 = h[3]  * C0.w;
        p0 *= e4; p1 *= e4; p2 *= e4; p3 *= e4;
        h[4]  = fmaf(h[4],  p0, dxv * B1.x); y0 = fmaf(h[4],  C1.x, y0);
        h[5]  = fmaf(h[5],  p1, dxv * B1.y); y1 = fmaf(h[5],  C1.y, y1);
        h[6]  = fmaf(h[6],  p2, dxv * B1.z); y2 = fmaf(h[6],  C1.z, y2);
        h[7]  = fmaf(h[7],  p3, dxv * B1.w); y3 = fmaf(h[7],  C1.w, y3);
        p0 *= e4; p1 *= e4; p2 *= e4; p3 *= e4;
        h[8]  = fmaf(h[8],  p0, dxv * B2.x); y0 = fmaf(h[8],  C2.x, y0);
        h[9]  = fmaf(h[9],  p1, dxv * B2.y); y1 = fmaf(h[9],  C2.y, y1);
        h[10] = fmaf(h[10], p2, dxv * B2.z); y2 = fmaf(h[10], C2.z, y2);
        h[11] = fmaf(h[11], p3, dxv * B2.w); y3 = fmaf(h[11], C2.w, y3);
        p0 *= e4; p1 *= e4; p2 *= e4; p3 *= e4;
        h[12] = fmaf(h[12], p0, dxv * B3.x); y0 = fmaf(h[12], C3.x, y0);
        h[13] = fmaf(h[13], p1, dxv * B3.y); y1 = fmaf(h[13], C3.y, y1);
        h[14] = fmaf(h[14], p2, dxv * B3.z); y2 = fmaf(h[14], C3.z, y2);
        h[15] = fmaf(h[15], p3, dxv * B3.w); y3 = fmaf(h[15], C3.w, y3);

        const float y  = (y0 + y1) + (y2 + y3);
        const float yv = fmaf(Dv, xcv[i], y);
        y_p[(size_t)i * DIMD] = f2bf(yv * zg[i]);
    }
}

extern "C" void kernel_launch(void* const* d_in, const int* in_sizes, int n_in,
                              void* d_out, int out_size, void* d_ws, size_t ws_size,
                              hipStream_t stream)
{
    const float* x          = (const float*)d_in[0];
    const float* in_proj_w  = (const float*)d_in[1];
    const float* conv_w     = (const float*)d_in[2];
    const float* conv_b     = (const float*)d_in[3];
    const float* x_proj_w   = (const float*)d_in[4];
    const float* D_param    = (const float*)d_in[5];
    const float* out_proj_w = (const float*)d_in[6];
    float* out = (float*)d_out;

    // workspace layout (xcraw slot retired — conv fused into GEMM1)
    float* xcraw = (float*)d_ws;                              // (unused)
    float* xc    = xcraw + (size_t)ML * DIMD;                 // ML*DIMD f32
    float* xdbl  = xc    + (size_t)ML * DIMD;                 // ML*XD_N f32
    unsigned short* zb  = (unsigned short*)(xdbl + (size_t)ML * XD_N); // ML*DIMD bf16
    unsigned short* xb  = zb  + (size_t)ML * DIMD;            // ML*DIMD bf16
    unsigned short* xcb = xb  + (size_t)ML * DIMD;            // ML*DIMD bf16
    unsigned short* wb1 = xcb + (size_t)ML * DIMD;            // XZ_N*DIMD bf16
    unsigned short* wb2 = wb1 + (size_t)XZ_N * DIMD;          // XD_N*DIMD bf16
    unsigned short* wb3 = wb2 + (size_t)XD_N * DIMD;          // DIMD*DIMD bf16
    float* hfin = (float*)(wb3 + (size_t)DIMD * DIMD);        // B*NC*DIMD*NS f32
    float* Ssum = hfin + (size_t)BB * NC * DIMD * NS;         // B*NC*DIMD f32
    unsigned short* yb  = xb;    // xb dead after GEMM1; reuse for scan output

    const int n0 = ML * DIMD / 4, n1 = XZ_N * DIMD / 4,
              n2 = XD_N * DIMD / 4, n3 = DIMD * DIMD / 4;
    const int ncvt = n0 + n1 + n2 + n3;

    // 0) all f32->bf16 conversions in one launch
    cvt_all<<<(ncvt + 255) / 256, 256, 0, stream>>>(
        x, xb, n0, in_proj_w, wb1, n1, x_proj_w, wb2, n2, out_proj_w, wb3, n3);

    // 1) xz = x @ in_proj_w.T, FUSED with depthwise conv+SiLU:
    //    x_c half -> conv -> xc (f32) + xcb (bf16); z half -> silu bf16 zb
    gemm_mfma_bt<true><<<dim3(XZ_N / 64, ML / 128), 256, 0, stream>>>(
        xb, wb1, nullptr, zb, conv_w, conv_b, xc, xcb, ML, XZ_N, DIMD, DIMD);

    // 2) x_dbl = xc @ x_proj_w.T     (4096 x 1056 x 1024)
    gemm_mfma_bt<false><<<dim3((XD_N + 63) / 64, ML / 128), 256, 0, stream>>>(
        xcb, wb2, xdbl, nullptr, nullptr, nullptr, nullptr, nullptr,
        ML, XD_N, DIMD, XD_N);

    // 3) chunked selective scan (LC=16). Do NOT grid.sync-fuse (prior session:
    //    grid sync forces per-XCD L2 writeback -> 577 MB HBM, 465 us).
    scan_part1<<<(BB * NC * DIMD) / 256, 256, 0, stream>>>(xdbl, xc, hfin, Ssum);
    scan_combine<<<(BB * DIMD) / 2, 256, 0, stream>>>(hfin, Ssum);
    scan_part2<<<(BB * NC * DIMD) / 256, 256, 0, stream>>>(xdbl, xc, zb, hfin,
                                                           D_param, yb);

    // 4) out = y @ out_proj_w.T      (4096 x 1024 x 1024)
    gemm_mfma_bt<false><<<dim3(DIMD / 64, ML / 128), 256, 0, stream>>>(
        yb, wb3, out, nullptr, nullptr, nullptr, nullptr, nullptr,
        ML, DIMD, DIMD, DIMD);
}